// Round 2
// baseline (300.178 us; speedup 1.0000x reference)
//
#include <hip/hip_runtime.h>

// Block-circulant matmul via FFT, round 5 (resubmit — harness failed twice,
// kernel never measured): 2 batch rows per block.
// Same fused radix-16-pair FFT as round 4, but each block now owns TWO batch
// rows (grid 8192 -> 4096). Twiddles + all addressing are computed once and
// applied to both rows (amortizes ~130 VALU ops/thread/row), each Wc4 float4
// load feeds 16 FMAs instead of 8 (halves L2 traffic for Wc4), and the two
// independent rows double per-thread ILP in the dependency-chained butterfly
// stages (compensates occupancy 16->8 waves/CU; LDS 76 KiB -> 2 blocks/CU).
// Matmul rebalanced: f = t&127, i-half = t>>7 (uniform); f=128 handled by 16
// lanes of wave 1 (~300 cyc) instead of the old 2.6K-cycle serial lane-0/128
// tails.
// Wave-owned regions: each wave loads + FFTs only its own 4 FFT regions (both
// rows), so load->fft->scatter and ifft->store need NO barriers.
// Only 3 barriers/block (around the cross-wave frequency matmul).
// LDS: Ar/Ai [2*16*304] floats = 76 KiB total; phys() swizzle keeps b32
// phases <=2-way.

#define TWO_PI 6.283185307179586f
constexpr int RS = 304;        // region stride (mod 32 == 16 -> 2-way across regions)
constexpr int RO = 16 * RS;    // row offset (floats) inside Ar/Ai

__device__ __forceinline__ int phys(int a) { return a + ((a >> 5) << 2); }

// (vr,vi) *= e^{-i*SGN*alpha}, where (c,s) = (cos alpha, sin alpha)
template<int SGN>
__device__ __forceinline__ void twmul(float& vr, float& vi, float c, float s)
{
    float r = vr * c + SGN * (vi * s);
    float i = vi * c - SGN * (vr * s);
    vr = r; vi = i;
}

// Pair 1 = DIF stages D=64 and D=16 for BOTH rows (twiddles shared).
// Elements: position u + 16m + 64k <-> register s = m + 4k.
template<int SGN, bool REAL>
__device__ __forceinline__ void pair1(float* __restrict__ Ar, float* __restrict__ Ai,
                                      int base, int u)
{
    float xr[2][16], xi[2][16];
#pragma unroll
    for (int r = 0; r < 2; ++r)
#pragma unroll
        for (int s = 0; s < 16; ++s) {
            int a = base + r * RO + phys(u + 16 * s);
            xr[r][s] = Ar[a];
            if (!REAL) xi[r][s] = Ai[a];
        }
    // ---- twiddles (depend only on u -> computed ONCE for both rows)
    float su, cu;
    __sincosf((float)u * (TWO_PI / 256.f), &su, &cu);
    const float CM[4] = {1.f, 0.92387953f, 0.70710678f, 0.38268343f};
    const float SM[4] = {0.f, 0.38268343f, 0.70710678f, 0.92387953f};
    float c1[4], s1[4], c2[4], s2[4], c3[4], s3[4];
#pragma unroll
    for (int m = 0; m < 4; ++m) {
        c1[m] = cu * CM[m] - su * SM[m];
        s1[m] = su * CM[m] + cu * SM[m];
        c2[m] = c1[m] * c1[m] - s1[m] * s1[m];
        s2[m] = 2.f * c1[m] * s1[m];
        c3[m] = c2[m] * c1[m] - s2[m] * s1[m];
        s3[m] = s2[m] * c1[m] + c2[m] * s1[m];
    }
    float cb1 = cu * cu - su * su, sb1 = 2.f * cu * su;                  // 2th
    { float c = cb1, s = sb1; cb1 = c * c - s * s; sb1 = 2.f * c * s; }  // 4th
    float cb2 = cb1 * cb1 - sb1 * sb1, sb2 = 2.f * cb1 * sb1;            // 8th
    float cb3 = cb2 * cb1 - sb2 * sb1, sb3 = sb2 * cb1 + cb2 * sb1;      // 12th

#pragma unroll
    for (int r = 0; r < 2; ++r) {
        // stage A (D=64): A_k = x[m+4k]
#pragma unroll
        for (int m = 0; m < 4; ++m) {
            if (REAL) {
                float a0 = xr[r][m], a1 = xr[r][m + 4], a2 = xr[r][m + 8], a3 = xr[r][m + 12];
                float t0 = a0 + a2, t1 = a0 - a2, t2 = a1 + a3, t3 = a1 - a3;
                xr[r][m] = t0 + t2;  xi[r][m] = 0.f;
                xr[r][m + 4]  = t1 * c1[m] - t3 * s1[m];
                xi[r][m + 4]  = -SGN * (t3 * c1[m] + t1 * s1[m]);
                float dd      = t0 - t2;
                xr[r][m + 8]  = dd * c2[m];
                xi[r][m + 8]  = -SGN * (dd * s2[m]);
                xr[r][m + 12] = t1 * c3[m] + t3 * s3[m];
                xi[r][m + 12] = SGN * (t3 * c3[m] - t1 * s3[m]);
            } else {
                float t0r = xr[r][m] + xr[r][m + 8],       t0i = xi[r][m] + xi[r][m + 8];
                float t1r = xr[r][m] - xr[r][m + 8],       t1i = xi[r][m] - xi[r][m + 8];
                float t2r = xr[r][m + 4] + xr[r][m + 12],  t2i = xi[r][m + 4] + xi[r][m + 12];
                float t3r = xr[r][m + 4] - xr[r][m + 12],  t3i = xi[r][m + 4] - xi[r][m + 12];
                xr[r][m] = t0r + t2r;  xi[r][m] = t0i + t2i;
                float v1r = t1r + SGN * t3i, v1i = t1i - SGN * t3r;
                float v2r = t0r - t2r,       v2i = t0i - t2i;
                float v3r = t1r - SGN * t3i, v3i = t1i + SGN * t3r;
                twmul<SGN>(v1r, v1i, c1[m], s1[m]);
                twmul<SGN>(v2r, v2i, c2[m], s2[m]);
                twmul<SGN>(v3r, v3i, c3[m], s3[m]);
                xr[r][m + 4]  = v1r; xi[r][m + 4]  = v1i;
                xr[r][m + 8]  = v2r; xi[r][m + 8]  = v2i;
                xr[r][m + 12] = v3r; xi[r][m + 12] = v3i;
            }
        }
        // stage B (D=16): A_m = x[4k+m], twiddle angles 4th, 8th, 12th
#pragma unroll
        for (int k = 0; k < 4; ++k) {
            int s0 = 4 * k;
            float t0r = xr[r][s0] + xr[r][s0 + 2],     t0i = xi[r][s0] + xi[r][s0 + 2];
            float t1r = xr[r][s0] - xr[r][s0 + 2],     t1i = xi[r][s0] - xi[r][s0 + 2];
            float t2r = xr[r][s0 + 1] + xr[r][s0 + 3], t2i = xi[r][s0 + 1] + xi[r][s0 + 3];
            float t3r = xr[r][s0 + 1] - xr[r][s0 + 3], t3i = xi[r][s0 + 1] - xi[r][s0 + 3];
            xr[r][s0] = t0r + t2r;  xi[r][s0] = t0i + t2i;
            float v1r = t1r + SGN * t3i, v1i = t1i - SGN * t3r;
            float v2r = t0r - t2r,       v2i = t0i - t2i;
            float v3r = t1r - SGN * t3i, v3i = t1i + SGN * t3r;
            twmul<SGN>(v1r, v1i, cb1, sb1);
            twmul<SGN>(v2r, v2i, cb2, sb2);
            twmul<SGN>(v3r, v3i, cb3, sb3);
            xr[r][s0 + 1] = v1r; xi[r][s0 + 1] = v1i;
            xr[r][s0 + 2] = v2r; xi[r][s0 + 2] = v2i;
            xr[r][s0 + 3] = v3r; xi[r][s0 + 3] = v3i;
        }
    }
#pragma unroll
    for (int r = 0; r < 2; ++r)
#pragma unroll
        for (int s = 0; s < 16; ++s) {
            int a = base + r * RO + phys(u + 16 * s);
            Ar[a] = xr[r][s]; Ai[a] = xi[r][s];
        }
}

// Pair 2 = DIF stages D=4 and D=1 for BOTH rows. Position 16u + s.
// STORE_REV: scatter outputs to rev4(position) (natural-order spectrum).
// REAL_OUT: final inverse pair - compute/store real part only, contiguous.
template<int SGN, bool STORE_REV, bool REAL_OUT>
__device__ __forceinline__ void pair2(float* __restrict__ Ar, float* __restrict__ Ai,
                                      int base, int u)
{
    int a0 = base + 16 * u + ((u >> 1) << 2);   // == base + phys(16u), contiguous run
    float xr[2][16], xi[2][16];
#pragma unroll
    for (int r = 0; r < 2; ++r)
#pragma unroll
        for (int v = 0; v < 4; ++v) {
            float4 vr = *(const float4*)(Ar + a0 + r * RO + 4 * v);
            float4 vi = *(const float4*)(Ai + a0 + r * RO + 4 * v);
            xr[r][4 * v] = vr.x; xr[r][4 * v + 1] = vr.y; xr[r][4 * v + 2] = vr.z; xr[r][4 * v + 3] = vr.w;
            xi[r][4 * v] = vi.x; xi[r][4 * v + 1] = vi.y; xi[r][4 * v + 2] = vi.z; xi[r][4 * v + 3] = vi.w;
        }
    const float CQ[4][4] = {
        {1.f, 1.f, 1.f, 1.f},
        {1.f, 0.92387953f, 0.70710678f, 0.38268343f},
        {1.f, 0.70710678f, 0.f, -0.70710678f},
        {1.f, 0.38268343f, -0.70710678f, -0.92387953f}};
    const float SQ[4][4] = {
        {0.f, 0.f, 0.f, 0.f},
        {0.f, 0.38268343f, 0.70710678f, 0.92387953f},
        {0.f, 0.70710678f, 1.f, 0.70710678f},
        {0.f, 0.92387953f, 0.70710678f, -0.38268343f}};
#pragma unroll
    for (int r = 0; r < 2; ++r) {
        // stage C (D=4): A_m = x[q+4m], twiddle (c,s) of pi*q*r/8 (compile-time)
#pragma unroll
        for (int q = 0; q < 4; ++q) {
            float t0r = xr[r][q] + xr[r][q + 8],       t0i = xi[r][q] + xi[r][q + 8];
            float t1r = xr[r][q] - xr[r][q + 8],       t1i = xi[r][q] - xi[r][q + 8];
            float t2r = xr[r][q + 4] + xr[r][q + 12],  t2i = xi[r][q + 4] + xi[r][q + 12];
            float t3r = xr[r][q + 4] - xr[r][q + 12],  t3i = xi[r][q + 4] - xi[r][q + 12];
            xr[r][q] = t0r + t2r;  xi[r][q] = t0i + t2i;
            float v1r = t1r + SGN * t3i, v1i = t1i - SGN * t3r;
            float v2r = t0r - t2r,       v2i = t0i - t2i;
            float v3r = t1r - SGN * t3i, v3i = t1i + SGN * t3r;
            twmul<SGN>(v1r, v1i, CQ[q][1], SQ[q][1]);
            twmul<SGN>(v2r, v2i, CQ[q][2], SQ[q][2]);
            twmul<SGN>(v3r, v3i, CQ[q][3], SQ[q][3]);
            xr[r][q + 4]  = v1r; xi[r][q + 4]  = v1i;
            xr[r][q + 8]  = v2r; xi[r][q + 8]  = v2i;
            xr[r][q + 12] = v3r; xi[r][q + 12] = v3i;
        }
        // stage D (D=1): contiguous quads, no twiddle
#pragma unroll
        for (int g = 0; g < 4; ++g) {
            int s0 = 4 * g;
            float t0r = xr[r][s0] + xr[r][s0 + 2],     t1r = xr[r][s0] - xr[r][s0 + 2];
            float t2r = xr[r][s0 + 1] + xr[r][s0 + 3], t3r = xr[r][s0 + 1] - xr[r][s0 + 3];
            float t0i = xi[r][s0] + xi[r][s0 + 2],     t1i = xi[r][s0] - xi[r][s0 + 2];
            float t2i = xi[r][s0 + 1] + xi[r][s0 + 3], t3i = xi[r][s0 + 1] - xi[r][s0 + 3];
            xr[r][s0]     = t0r + t2r;
            xr[r][s0 + 1] = t1r + SGN * t3i;
            xr[r][s0 + 2] = t0r - t2r;
            xr[r][s0 + 3] = t1r - SGN * t3i;
            if (!REAL_OUT) {
                xi[r][s0]     = t0i + t2i;
                xi[r][s0 + 1] = t1i - SGN * t3r;
                xi[r][s0 + 2] = t0i - t2i;
                xi[r][s0 + 3] = t1i + SGN * t3r;
            }
        }
    }
    if (STORE_REV) {
        int q2 = (u >> 2) + ((u & 3) << 2);
#pragma unroll
        for (int r = 0; r < 2; ++r)
#pragma unroll
            for (int s = 0; s < 16; ++s) {
                int dest = q2 + ((s >> 2) << 4) + ((s & 3) << 6);   // rev4(16u+s)
                int a = base + r * RO + phys(dest);
                Ar[a] = xr[r][s]; Ai[a] = xi[r][s];
            }
    } else {
#pragma unroll
        for (int r = 0; r < 2; ++r)
#pragma unroll
            for (int v = 0; v < 4; ++v) {
                *(float4*)(Ar + a0 + r * RO + 4 * v) =
                    make_float4(xr[r][4*v], xr[r][4*v+1], xr[r][4*v+2], xr[r][4*v+3]);
                if (!REAL_OUT)
                    *(float4*)(Ai + a0 + r * RO + 4 * v) =
                        make_float4(xi[r][4*v], xi[r][4*v+1], xi[r][4*v+2], xi[r][4*v+3]);
            }
    }
}

// Wc4[i][jc][f] = float4(Hc[f][i][2jc].re,.im, Hc[f][i][2jc+1].re,.im),
// f = 0..128 (pad 132), Hc = conj(FFT_256(W[i,j,:])). 270 KB in d_ws.
__global__ __launch_bounds__(256) void wfft_kernel(const float* __restrict__ W,
                                                   float* __restrict__ Wc4)
{
    __shared__ float wblk[256];
    __shared__ float tabc[256], tabs[256];
    int t   = threadIdx.x;                 // t = frequency f
    int blk = blockIdx.x;                  // blk = i*16 + j
    wblk[t] = W[blk * 256 + t];
    float s, c;
    __sincosf((float)t * (TWO_PI / 256.f), &s, &c);
    tabc[t] = c; tabs[t] = s;
    __syncthreads();
    if (t <= 128) {
        float ar = 0.f, ai = 0.f;
        for (int cc = 0; cc < 256; ++cc) {
            int idx = (t * cc) & 255;
            float wv = wblk[cc];
            ar = fmaf(wv, tabc[idx], ar);
            ai = fmaf(wv, tabs[idx], ai);
        }
        int i = blk >> 4, j = blk & 15;
        int flat = ((i * 8 + (j >> 1)) * 132 + t) * 4 + ((j & 1) << 1);
        Wc4[flat]     = ar;
        Wc4[flat + 1] = ai;
    }
}

__global__ __launch_bounds__(256, 2) void bc_kernel(const float* __restrict__ x,
                                                    const float* __restrict__ d,
                                                    const float* __restrict__ bias,
                                                    const float* __restrict__ Wc4,
                                                    float* __restrict__ out)
{
    __shared__ float Ar[2 * 16 * RS], Ai[2 * 16 * RS];   // 76 KiB total
    int t  = threadIdx.x;
    int b0 = blockIdx.x * 2;               // this block owns rows b0, b0+1
    int w = t >> 6, l = t & 63;
    int u = t & 15;
    int base = (t >> 4) * RS;              // region = 4w + (l>>4), wave-owned (row 0)

    // ---- load: wave w loads its own regions 4w..4w+3, BOTH rows (coalesced float4)
    const float4* d4 = (const float4*)d;
#pragma unroll
    for (int it = 0; it < 4; ++it) {
        int idx = 256 * w + 64 * it + l;
        float4 dv = d4[idx];
        int a = (4 * w + it) * RS + 4 * l + ((l >> 3) << 2);   // phys(4l)
#pragma unroll
        for (int r = 0; r < 2; ++r) {
            float4 xv = ((const float4*)(x + (size_t)(b0 + r) * 4096))[idx];
            *(float4*)(Ar + a + r * RO) =
                make_float4(xv.x * dv.x, xv.y * dv.y, xv.z * dv.z, xv.w * dv.w);
        }
    }
    // no barrier: regions are wave-private, DS ops in-order within a wave

    pair1<1, true>(Ar, Ai, base, u);
    pair2<1, true, false>(Ar, Ai, base, u);   // scatter -> natural-order spectrum
    __syncthreads();                           // BAR 1: matmul reads cross-wave

    // ---- frequency matmul: f = t&127, i-half = t>>7; f=128 by 16 lanes of wave 1
    {
        int f  = t & 127;
        int pf = phys(f);
        float vr[2][16], vi[2][16];
#pragma unroll
        for (int r = 0; r < 2; ++r)
#pragma unroll
            for (int j = 0; j < 16; ++j) {
                vr[r][j] = Ar[r * RO + j * RS + pf];
                vi[r][j] = Ai[r * RO + j * RS + pf];
            }
        bool x128 = (t >= 64 && t < 80);       // wave-1 lanes 0..15 also own f=128
        int p8 = phys(128);
        float v8r[2][16], v8i[2][16];
        if (x128) {
#pragma unroll
            for (int r = 0; r < 2; ++r)
#pragma unroll
                for (int j = 0; j < 16; ++j) { // broadcast reads (same addr per lane)
                    v8r[r][j] = Ar[r * RO + j * RS + p8];
                    v8i[r][j] = Ai[r * RO + j * RS + p8];
                }
        }
        __syncthreads();                       // BAR 2: all reads before writes
        const float4* wb = (const float4*)Wc4;
        int ib = (t >> 7) * 8;
#pragma unroll
        for (int io = 0; io < 8; ++io) {
            int i = ib + io;
            float yr0 = 0.f, yi0 = 0.f, yr1 = 0.f, yi1 = 0.f;
#pragma unroll
            for (int jc = 0; jc < 8; ++jc) {
                float4 wv = wb[(i * 8 + jc) * 132 + f];
                int j0 = 2 * jc;
                yr0 = fmaf(vr[0][j0], wv.x, yr0); yr0 = fmaf(-vi[0][j0], wv.y, yr0);
                yi0 = fmaf(vr[0][j0], wv.y, yi0); yi0 = fmaf(vi[0][j0], wv.x, yi0);
                yr0 = fmaf(vr[0][j0+1], wv.z, yr0); yr0 = fmaf(-vi[0][j0+1], wv.w, yr0);
                yi0 = fmaf(vr[0][j0+1], wv.w, yi0); yi0 = fmaf(vi[0][j0+1], wv.z, yi0);
                yr1 = fmaf(vr[1][j0], wv.x, yr1); yr1 = fmaf(-vi[1][j0], wv.y, yr1);
                yi1 = fmaf(vr[1][j0], wv.y, yi1); yi1 = fmaf(vi[1][j0], wv.x, yi1);
                yr1 = fmaf(vr[1][j0+1], wv.z, yr1); yr1 = fmaf(-vi[1][j0+1], wv.w, yr1);
                yi1 = fmaf(vr[1][j0+1], wv.w, yi1); yi1 = fmaf(vi[1][j0+1], wv.z, yi1);
            }
            Ar[i * RS + pf] = yr0;        Ai[i * RS + pf] = yi0;
            Ar[RO + i * RS + pf] = yr1;   Ai[RO + i * RS + pf] = yi1;
            if (f >= 1) {                  // f in 1..127: conjugate symmetry fills
                int pc = phys(256 - f);
                Ar[i * RS + pc] = yr0;       Ai[i * RS + pc] = -yi0;
                Ar[RO + i * RS + pc] = yr1;  Ai[RO + i * RS + pc] = -yi1;
            }
        }
        if (x128) {                        // f=128, i = t-64, both rows
            int i = t - 64;
#pragma unroll
            for (int r = 0; r < 2; ++r) {
                float yr = 0.f, yi = 0.f;
#pragma unroll
                for (int jc = 0; jc < 8; ++jc) {
                    float4 wv = wb[(i * 8 + jc) * 132 + 128];
                    int j0 = 2 * jc;
                    yr = fmaf(v8r[r][j0], wv.x, yr); yr = fmaf(-v8i[r][j0], wv.y, yr);
                    yi = fmaf(v8r[r][j0], wv.y, yi); yi = fmaf(v8i[r][j0], wv.x, yi);
                    yr = fmaf(v8r[r][j0+1], wv.z, yr); yr = fmaf(-v8i[r][j0+1], wv.w, yr);
                    yi = fmaf(v8r[r][j0+1], wv.w, yi); yi = fmaf(v8i[r][j0+1], wv.z, yi);
                }
                Ar[r * RO + i * RS + p8] = yr;
                Ai[r * RO + i * RS + p8] = yi;
            }
        }
    }
    __syncthreads();                           // BAR 3

    pair1<-1, false>(Ar, Ai, base, u);
    pair2<-1, false, true>(Ar, Ai, base, u);   // real-only, contiguous store
    // no barrier: gather below reads own-wave regions only

    // ---- store: gather rev4 positions (b32, 2-way), coalesced float4 global
    const float4* b4 = (const float4*)bias;
    int dbase = ((l >> 4) & 3) + (((l >> 2) & 3) << 2) + ((l & 3) << 4);
#pragma unroll
    for (int it = 0; it < 4; ++it) {
        int idx = 256 * w + 64 * it + l;
        int rb  = (4 * w + it) * RS;
        float4 bv = b4[idx];
#pragma unroll
        for (int r = 0; r < 2; ++r) {
            float vv[4];
#pragma unroll
            for (int e = 0; e < 4; ++e) {
                int dest = dbase + (e << 6);   // rev4(4l+e)
                vv[e] = Ar[r * RO + rb + phys(dest)];
            }
            float4 ov;
            ov.x = vv[0] * (1.f / 256.f) + bv.x;
            ov.y = vv[1] * (1.f / 256.f) + bv.y;
            ov.z = vv[2] * (1.f / 256.f) + bv.z;
            ov.w = vv[3] * (1.f / 256.f) + bv.w;
            ((float4*)(out + (size_t)(b0 + r) * 4096))[idx] = ov;
        }
    }
}

extern "C" void kernel_launch(void* const* d_in, const int* in_sizes, int n_in,
                              void* d_out, int out_size, void* d_ws, size_t ws_size,
                              hipStream_t stream)
{
    const float* x    = (const float*)d_in[0];   // (8192, 4096)
    const float* W    = (const float*)d_in[1];   // (16, 16, 256)
    const float* d    = (const float*)d_in[2];   // (4096,)
    const float* bias = (const float*)d_in[3];   // (4096,)
    float* out = (float*)d_out;
    float* Wc4 = (float*)d_ws;                   // [16][8][132] float4 = 270 KB

    wfft_kernel<<<256, 256, 0, stream>>>(W, Wc4);
    bc_kernel<<<4096, 256, 0, stream>>>(x, d, bias, Wc4, out);
}